// Round 1
// baseline (533.031 us; speedup 1.0000x reference)
//
#include <hip/hip_runtime.h>
#include <hip/hip_bf16.h>

#define NN 100000
#define NE 3200000
#define FIN 128
#define HD 16
#define CD 2

#define BSH 8                        // bucket shift
#define BSPAN 256                    // nodes per bucket
#define NBKT 391                     // ceil(NN / BSPAN)
#define CHUNK 8192                   // edges per partition block
#define NPB ((NE + CHUNK - 1) / CHUNK)   // 391

__device__ __forceinline__ float bf2f(ushort u) {
    union { float f; unsigned int i; } v; v.i = ((unsigned int)u) << 16; return v.f;
}
__device__ __forceinline__ float lo2f(unsigned int u) {
    union { float f; unsigned int i; } v; v.i = u << 16; return v.f;
}
__device__ __forceinline__ float hi2f(unsigned int u) {
    union { float f; unsigned int i; } v; v.i = u & 0xFFFF0000u; return v.f;
}
__device__ __forceinline__ ushort f2b(float f) {
    union { float f; unsigned int u; } v; v.f = f;
    unsigned int r = (v.u + 0x7FFFu + ((v.u >> 16) & 1u)) >> 16;   // RNE
    return (ushort)r;
}

// ---- pass 1: per-block bucket counts -> cntmat[b][bucket] ----
__global__ __launch_bounds__(512) void k_cnt(const int* __restrict__ dst,
                                             int* __restrict__ cntmat) {
    __shared__ int h[NBKT];
    for (int i = threadIdx.x; i < NBKT; i += 512) h[i] = 0;
    __syncthreads();
    int cq = blockIdx.x * (CHUNK / 4);
    const int4* d4 = (const int4*)dst;
    #pragma unroll
    for (int j = 0; j < CHUNK / 2048; ++j) {
        int e4 = cq + j * 512 + threadIdx.x;
        if (e4 < NE / 4) {
            int4 d = d4[e4];
            atomicAdd(&h[d.x >> BSH], 1);
            atomicAdd(&h[d.y >> BSH], 1);
            atomicAdd(&h[d.z >> BSH], 1);
            atomicAdd(&h[d.w >> BSH], 1);
        }
    }
    __syncthreads();
    int* row = cntmat + (size_t)blockIdx.x * NBKT;
    for (int i = threadIdx.x; i < NBKT; i += 512) row[i] = h[i];
}

// ---- pass 2: column-wise exclusive scan -> relm[bucket][b], btot ----
__global__ __launch_bounds__(256) void k_colscan(const int* __restrict__ cntmat,
                                                 int* __restrict__ relm,
                                                 int* __restrict__ btot) {
    __shared__ int sm[256];
    int j = blockIdx.x, t = threadIdx.x;
    int v[2];
    int b0 = t * 2;
    #pragma unroll
    for (int k = 0; k < 2; ++k) {
        int b = b0 + k;
        v[k] = (b < NPB) ? cntmat[(size_t)b * NBKT + j] : 0;
    }
    sm[t] = v[0] + v[1];
    __syncthreads();
    for (int off = 1; off < 256; off <<= 1) {
        int x = 0;
        if (t >= off) x = sm[t - off];
        __syncthreads();
        if (t >= off) sm[t] += x;
        __syncthreads();
    }
    int run = (t == 0) ? 0 : sm[t - 1];
    int* rrow = relm + (size_t)j * NPB;
    #pragma unroll
    for (int k = 0; k < 2; ++k) {
        int b = b0 + k;
        if (b < NPB) rrow[b] = run;
        run += v[k];
    }
    if (t == 255) btot[j] = sm[255];
}

// ---- pass 3: scan bucket totals -> boff ----
__global__ __launch_bounds__(512) void k_scanb(const int* __restrict__ btot,
                                               int* __restrict__ boff) {
    __shared__ int sm[512];
    int t = threadIdx.x;
    sm[t] = (t < NBKT) ? btot[t] : 0;
    __syncthreads();
    for (int off = 1; off < 512; off <<= 1) {
        int v = 0;
        if (t >= off) v = sm[t - off];
        __syncthreads();
        if (t >= off) sm[t] += v;
        __syncthreads();
    }
    if (t < NBKT) boff[t] = t ? sm[t - 1] : 0;
    if (t == 511) boff[NBKT] = sm[511];   // = NE
}

// ---- pass 4: deterministic partition, single edge pass ----
__global__ __launch_bounds__(512) void k_part(const int* __restrict__ src,
                                              const int* __restrict__ dst,
                                              const int* __restrict__ boff,
                                              const int* __restrict__ relm,
                                              unsigned int* __restrict__ csrb) {
    __shared__ int cur[NBKT];
    int b = blockIdx.x, t = threadIdx.x;
    for (int i = t; i < NBKT; i += 512)
        cur[i] = boff[i] + relm[(size_t)i * NPB + b];
    __syncthreads();
    int cq = b * (CHUNK / 4);
    const int4* s4 = (const int4*)src;
    const int4* d4 = (const int4*)dst;
    #pragma unroll
    for (int j = 0; j < CHUNK / 2048; ++j) {
        int e4 = cq + j * 512 + t;
        if (e4 < NE / 4) {
            int4 s = s4[e4];
            int4 d = d4[e4];
            int p;
            p = atomicAdd(&cur[d.x >> BSH], 1);
            csrb[p] = (unsigned)s.x | ((unsigned)(d.x & (BSPAN - 1)) << 17);
            p = atomicAdd(&cur[d.y >> BSH], 1);
            csrb[p] = (unsigned)s.y | ((unsigned)(d.y & (BSPAN - 1)) << 17);
            p = atomicAdd(&cur[d.z >> BSH], 1);
            csrb[p] = (unsigned)s.z | ((unsigned)(d.z & (BSPAN - 1)) << 17);
            p = atomicAdd(&cur[d.w >> BSH], 1);
            csrb[p] = (unsigned)s.w | ((unsigned)(d.w & (BSPAN - 1)) << 17);
        }
    }
}

// ---- per-bucket degree count -> dinv (all edges of a node live in its bucket) ----
__global__ __launch_bounds__(512) void k_deg(const int* __restrict__ boff,
                                             const unsigned int* __restrict__ csrb,
                                             float* __restrict__ dinv) {
    __shared__ int cnt[BSPAN];
    int b = blockIdx.x, t = threadIdx.x;
    if (t < BSPAN) cnt[t] = 0;
    __syncthreads();
    int e0 = boff[b], e1 = boff[b + 1];
    for (int e = e0 + t; e < e1; e += 512) atomicAdd(&cnt[csrb[e] >> 17], 1);
    __syncthreads();
    if (t < BSPAN) {
        int node = b * BSPAN + t;
        if (node < NN) dinv[node] = rsqrtf((float)cnt[t] + 1.0f);
    }
}

// ---- h1b = bf16((x @ W1) * dinv[node]) : 4 threads/node, 4 outputs each ----
__global__ __launch_bounds__(256) void k_gemm1(const float* __restrict__ x,
                                               const float* __restrict__ W1,
                                               const float* __restrict__ dinv,
                                               ushort* __restrict__ h1b) {
    __shared__ float wsm[FIN][HD];   // 8 KB
    for (int i = threadIdx.x; i < FIN * HD; i += 256) wsm[i >> 4][i & 15] = W1[i];
    __syncthreads();
    int t = blockIdx.x * 256 + threadIdx.x;
    int node = t >> 2;
    if (node >= NN) return;
    int g = (t & 3) * 4;
    const float4* xr = (const float4*)(x + (size_t)node * FIN);
    float a0 = 0.f, a1 = 0.f, a2 = 0.f, a3 = 0.f;
    #pragma unroll
    for (int k4 = 0; k4 < FIN / 4; ++k4) {
        float4 v = xr[k4];
        #pragma unroll
        for (int kk = 0; kk < 4; ++kk) {
            float vk = (kk == 0) ? v.x : (kk == 1) ? v.y : (kk == 2) ? v.z : v.w;
            float4 w = *(const float4*)&wsm[k4 * 4 + kk][g];
            a0 += vk * w.x;
            a1 += vk * w.y;
            a2 += vk * w.z;
            a3 += vk * w.w;
        }
    }
    float di = dinv[node];
    ushort4 r = {f2b(a0 * di), f2b(a1 * di), f2b(a2 * di), f2b(a3 * di)};
    *(ushort4*)(h1b + (size_t)node * HD + g) = r;
}

// ---- layer-1: per-bucket LDS scatter-accumulate + ReLU + fused (h2 @ W2)*dinv ----
// one thread per edge: gather 32B h1b row, 16x ds_add_f32 into acc[256][17]
__global__ __launch_bounds__(512) void k_aggs1(const int* __restrict__ boff,
                                               const unsigned int* __restrict__ csrb,
                                               const ushort* __restrict__ h1b,
                                               const float* __restrict__ dinv,
                                               const float* __restrict__ b1,
                                               const float* __restrict__ W2,
                                               float* __restrict__ g_s) {
    __shared__ float acc[BSPAN][HD + 1];   // 17.4 KB, stride-17 spreads banks
    __shared__ float w2s[HD * 2];
    __shared__ float b1s[HD];
    int b = blockIdx.x, t = threadIdx.x;
    for (int i = t; i < BSPAN * (HD + 1); i += 512) ((float*)acc)[i] = 0.f;
    if (t < HD * 2) w2s[t] = W2[t];
    else if (t < HD * 3) b1s[t - HD * 2] = b1[t - HD * 2];
    __syncthreads();
    int e0 = boff[b], e1 = boff[b + 1];
    for (int e = e0 + t; e < e1; e += 512) {
        unsigned p = csrb[e];
        int s = p & 0x1FFFF;
        float* a = acc[p >> 17];
        const uint4* r = (const uint4*)(h1b + (size_t)s * HD);
        uint4 u0 = r[0];
        uint4 u1 = r[1];
        atomicAdd(a + 0,  lo2f(u0.x)); atomicAdd(a + 1,  hi2f(u0.x));
        atomicAdd(a + 2,  lo2f(u0.y)); atomicAdd(a + 3,  hi2f(u0.y));
        atomicAdd(a + 4,  lo2f(u0.z)); atomicAdd(a + 5,  hi2f(u0.z));
        atomicAdd(a + 6,  lo2f(u0.w)); atomicAdd(a + 7,  hi2f(u0.w));
        atomicAdd(a + 8,  lo2f(u1.x)); atomicAdd(a + 9,  hi2f(u1.x));
        atomicAdd(a + 10, lo2f(u1.y)); atomicAdd(a + 11, hi2f(u1.y));
        atomicAdd(a + 12, lo2f(u1.z)); atomicAdd(a + 13, hi2f(u1.z));
        atomicAdd(a + 14, lo2f(u1.w)); atomicAdd(a + 15, hi2f(u1.w));
    }
    __syncthreads();
    // epilogue: 2 threads per node (8 features each), pair-reduce via shfl
    int loc = t >> 1, half = t & 1;
    int node = b * BSPAN + loc;
    if (node < NN) {
        float di = dinv[node];
        const uint4 sv = *(const uint4*)(h1b + (size_t)node * HD + half * 8);
        float s0 = lo2f(sv.x), s1 = hi2f(sv.x), s2 = lo2f(sv.y), s3 = hi2f(sv.y);
        float s4 = lo2f(sv.z), s5 = hi2f(sv.z), s6 = lo2f(sv.w), s7 = hi2f(sv.w);
        const float* a = acc[loc] + half * 8;
        const float* bb = b1s + half * 8;
        const float* ww = w2s + half * 16;
        float sf[8] = {s0, s1, s2, s3, s4, s5, s6, s7};
        float p0 = 0.f, p1 = 0.f;
        #pragma unroll
        for (int k = 0; k < 8; ++k) {
            float v = fmaxf(di * (a[k] + sf[k]) + bb[k], 0.f);
            p0 += v * ww[k * 2];
            p1 += v * ww[k * 2 + 1];
        }
        p0 += __shfl_xor(p0, 1, 64);
        p1 += __shfl_xor(p1, 1, 64);
        if (half == 0) {
            float2 r = {p0 * di, p1 * di};
            *(float2*)(g_s + (size_t)node * 2) = r;
        }
    }
}

// ---- layer-2: per-bucket LDS scatter-accumulate + bias + fused log_softmax ----
__global__ __launch_bounds__(512) void k_aggs2(const int* __restrict__ boff,
                                               const unsigned int* __restrict__ csrb,
                                               const float* __restrict__ g_s,
                                               const float* __restrict__ dinv,
                                               const float* __restrict__ b2,
                                               float* __restrict__ out) {
    __shared__ float acc[BSPAN * 3];   // stride-3 spreads banks
    int b = blockIdx.x, t = threadIdx.x;
    for (int i = t; i < BSPAN * 3; i += 512) acc[i] = 0.f;
    __syncthreads();
    int e0 = boff[b], e1 = boff[b + 1];
    for (int e = e0 + t; e < e1; e += 512) {
        unsigned p = csrb[e];
        int s = p & 0x1FFFF;
        int loc = p >> 17;
        float2 v = *(const float2*)(g_s + (size_t)s * 2);
        atomicAdd(&acc[loc * 3], v.x);
        atomicAdd(&acc[loc * 3 + 1], v.y);
    }
    __syncthreads();
    if (t < BSPAN) {
        int node = b * BSPAN + t;
        if (node < NN) {
            float di = dinv[node];
            float2 sv = *(const float2*)(g_s + (size_t)node * 2);
            float o0 = di * (acc[t * 3] + sv.x) + b2[0];
            float o1 = di * (acc[t * 3 + 1] + sv.y) + b2[1];
            float mx = fmaxf(o0, o1);
            float l = mx + logf(__expf(o0 - mx) + __expf(o1 - mx));
            float2 r = {o0 - l, o1 - l};
            *(float2*)(out + (size_t)node * 2) = r;
        }
    }
}

extern "C" void kernel_launch(void* const* d_in, const int* in_sizes, int n_in,
                              void* d_out, int out_size, void* d_ws, size_t ws_size,
                              hipStream_t stream) {
    const float* x   = (const float*)d_in[0];
    const int* ei    = (const int*)d_in[1];
    const int* src   = ei;
    const int* dst   = ei + NE;
    const float* W1  = (const float*)d_in[2];
    const float* b1  = (const float*)d_in[3];
    const float* W2  = (const float*)d_in[4];
    const float* b2  = (const float*)d_in[5];
    float* out = (float*)d_out;

    char* w = (char*)d_ws;
    float* dinv        = (float*)w;          w += NN * 4;
    int*   btot        = (int*)w;            w += NBKT * 4;
    int*   boff        = (int*)w;            w += (NBKT + 1) * 4;
    int*   cntmat      = (int*)w;            w += (size_t)NPB * NBKT * 4;   // 611 KB
    int*   relm        = (int*)w;            w += (size_t)NBKT * NPB * 4;   // 611 KB
    unsigned int* csrb = (unsigned int*)w;   w += (size_t)NE * 4;           // 12.8 MB
    ushort* h1b        = (ushort*)w;         w += (size_t)NN * HD * 2;      // 3.2 MB
    float* g_s         = (float*)w;          w += NN * CD * 4;

    k_cnt    <<<NPB, 512, 0, stream>>>(dst, cntmat);
    k_colscan<<<NBKT, 256, 0, stream>>>(cntmat, relm, btot);
    k_scanb  <<<1, 512, 0, stream>>>(btot, boff);
    k_part   <<<NPB, 512, 0, stream>>>(src, dst, boff, relm, csrb);
    k_deg    <<<NBKT, 512, 0, stream>>>(boff, csrb, dinv);
    k_gemm1  <<<(NN * 4 + 255) / 256, 256, 0, stream>>>(x, W1, dinv, h1b);
    k_aggs1  <<<NBKT, 512, 0, stream>>>(boff, csrb, h1b, dinv, b1, W2, g_s);
    k_aggs2  <<<NBKT, 512, 0, stream>>>(boff, csrb, g_s, dinv, b2, out);
}

// Round 2
// 205.673 us; speedup vs baseline: 2.5916x; 2.5916x over previous
//
#include <hip/hip_runtime.h>
#include <hip/hip_bf16.h>

#define NN 100000
#define NE 3200000
#define FIN 128
#define HD 16
#define CD 2

#define BSH 8                        // bucket shift
#define BSPAN 256                    // nodes per bucket
#define NBKT 391                     // ceil(NN / BSPAN)
#define CHUNK 8192                   // edges per partition block
#define NPB ((NE + CHUNK - 1) / CHUNK)   // 391

#define FXS 1048576.0f               // 2^20 fixed-point scale
#define FXI (1.0f / 1048576.0f)

__device__ __forceinline__ float bf2f(ushort u) {
    union { float f; unsigned int i; } v; v.i = ((unsigned int)u) << 16; return v.f;
}
__device__ __forceinline__ float lo2f(unsigned int u) {
    union { float f; unsigned int i; } v; v.i = u << 16; return v.f;
}
__device__ __forceinline__ float hi2f(unsigned int u) {
    union { float f; unsigned int i; } v; v.i = u & 0xFFFF0000u; return v.f;
}
__device__ __forceinline__ ushort f2b(float f) {
    union { float f; unsigned int u; } v; v.f = f;
    unsigned int r = (v.u + 0x7FFFu + ((v.u >> 16) & 1u)) >> 16;   // RNE
    return (ushort)r;
}

// ---- pass 1: per-block bucket counts -> cntmat[b][bucket] ----
__global__ __launch_bounds__(512) void k_cnt(const int* __restrict__ dst,
                                             int* __restrict__ cntmat) {
    __shared__ int h[NBKT];
    for (int i = threadIdx.x; i < NBKT; i += 512) h[i] = 0;
    __syncthreads();
    int cq = blockIdx.x * (CHUNK / 4);
    const int4* d4 = (const int4*)dst;
    #pragma unroll
    for (int j = 0; j < CHUNK / 2048; ++j) {
        int e4 = cq + j * 512 + threadIdx.x;
        if (e4 < NE / 4) {
            int4 d = d4[e4];
            atomicAdd(&h[d.x >> BSH], 1);
            atomicAdd(&h[d.y >> BSH], 1);
            atomicAdd(&h[d.z >> BSH], 1);
            atomicAdd(&h[d.w >> BSH], 1);
        }
    }
    __syncthreads();
    int* row = cntmat + (size_t)blockIdx.x * NBKT;
    for (int i = threadIdx.x; i < NBKT; i += 512) row[i] = h[i];
}

// ---- pass 2: column-wise exclusive scan -> relm[bucket][b], btot ----
__global__ __launch_bounds__(256) void k_colscan(const int* __restrict__ cntmat,
                                                 int* __restrict__ relm,
                                                 int* __restrict__ btot) {
    __shared__ int sm[256];
    int j = blockIdx.x, t = threadIdx.x;
    int v[2];
    int b0 = t * 2;
    #pragma unroll
    for (int k = 0; k < 2; ++k) {
        int b = b0 + k;
        v[k] = (b < NPB) ? cntmat[(size_t)b * NBKT + j] : 0;
    }
    sm[t] = v[0] + v[1];
    __syncthreads();
    for (int off = 1; off < 256; off <<= 1) {
        int x = 0;
        if (t >= off) x = sm[t - off];
        __syncthreads();
        if (t >= off) sm[t] += x;
        __syncthreads();
    }
    int run = (t == 0) ? 0 : sm[t - 1];
    int* rrow = relm + (size_t)j * NPB;
    #pragma unroll
    for (int k = 0; k < 2; ++k) {
        int b = b0 + k;
        if (b < NPB) rrow[b] = run;
        run += v[k];
    }
    if (t == 255) btot[j] = sm[255];
}

// ---- pass 3: scan bucket totals -> boff ----
__global__ __launch_bounds__(512) void k_scanb(const int* __restrict__ btot,
                                               int* __restrict__ boff) {
    __shared__ int sm[512];
    int t = threadIdx.x;
    sm[t] = (t < NBKT) ? btot[t] : 0;
    __syncthreads();
    for (int off = 1; off < 512; off <<= 1) {
        int v = 0;
        if (t >= off) v = sm[t - off];
        __syncthreads();
        if (t >= off) sm[t] += v;
        __syncthreads();
    }
    if (t < NBKT) boff[t] = t ? sm[t - 1] : 0;
    if (t == 511) boff[NBKT] = sm[511];   // = NE
}

// ---- pass 4: deterministic partition, single edge pass ----
__global__ __launch_bounds__(512) void k_part(const int* __restrict__ src,
                                              const int* __restrict__ dst,
                                              const int* __restrict__ boff,
                                              const int* __restrict__ relm,
                                              unsigned int* __restrict__ csrb) {
    __shared__ int cur[NBKT];
    int b = blockIdx.x, t = threadIdx.x;
    for (int i = t; i < NBKT; i += 512)
        cur[i] = boff[i] + relm[(size_t)i * NPB + b];
    __syncthreads();
    int cq = b * (CHUNK / 4);
    const int4* s4 = (const int4*)src;
    const int4* d4 = (const int4*)dst;
    #pragma unroll
    for (int j = 0; j < CHUNK / 2048; ++j) {
        int e4 = cq + j * 512 + t;
        if (e4 < NE / 4) {
            int4 s = s4[e4];
            int4 d = d4[e4];
            int p;
            p = atomicAdd(&cur[d.x >> BSH], 1);
            csrb[p] = (unsigned)s.x | ((unsigned)(d.x & (BSPAN - 1)) << 17);
            p = atomicAdd(&cur[d.y >> BSH], 1);
            csrb[p] = (unsigned)s.y | ((unsigned)(d.y & (BSPAN - 1)) << 17);
            p = atomicAdd(&cur[d.z >> BSH], 1);
            csrb[p] = (unsigned)s.z | ((unsigned)(d.z & (BSPAN - 1)) << 17);
            p = atomicAdd(&cur[d.w >> BSH], 1);
            csrb[p] = (unsigned)s.w | ((unsigned)(d.w & (BSPAN - 1)) << 17);
        }
    }
}

// ---- per-bucket degree count -> dinv (all edges of a node live in its bucket) ----
__global__ __launch_bounds__(512) void k_deg(const int* __restrict__ boff,
                                             const unsigned int* __restrict__ csrb,
                                             float* __restrict__ dinv) {
    __shared__ int cnt[BSPAN];
    int b = blockIdx.x, t = threadIdx.x;
    if (t < BSPAN) cnt[t] = 0;
    __syncthreads();
    int e0 = boff[b], e1 = boff[b + 1];
    for (int e = e0 + t; e < e1; e += 512) atomicAdd(&cnt[csrb[e] >> 17], 1);
    __syncthreads();
    if (t < BSPAN) {
        int node = b * BSPAN + t;
        if (node < NN) dinv[node] = rsqrtf((float)cnt[t] + 1.0f);
    }
}

// ---- h1b = bf16((x @ W1) * dinv[node]) : 4 threads/node, 4 outputs each ----
__global__ __launch_bounds__(256) void k_gemm1(const float* __restrict__ x,
                                               const float* __restrict__ W1,
                                               const float* __restrict__ dinv,
                                               ushort* __restrict__ h1b) {
    __shared__ float wsm[FIN][HD];   // 8 KB
    for (int i = threadIdx.x; i < FIN * HD; i += 256) wsm[i >> 4][i & 15] = W1[i];
    __syncthreads();
    int t = blockIdx.x * 256 + threadIdx.x;
    int node = t >> 2;
    if (node >= NN) return;
    int g = (t & 3) * 4;
    const float4* xr = (const float4*)(x + (size_t)node * FIN);
    float a0 = 0.f, a1 = 0.f, a2 = 0.f, a3 = 0.f;
    #pragma unroll
    for (int k4 = 0; k4 < FIN / 4; ++k4) {
        float4 v = xr[k4];
        #pragma unroll
        for (int kk = 0; kk < 4; ++kk) {
            float vk = (kk == 0) ? v.x : (kk == 1) ? v.y : (kk == 2) ? v.z : v.w;
            float4 w = *(const float4*)&wsm[k4 * 4 + kk][g];
            a0 += vk * w.x;
            a1 += vk * w.y;
            a2 += vk * w.z;
            a3 += vk * w.w;
        }
    }
    float di = dinv[node];
    ushort4 r = {f2b(a0 * di), f2b(a1 * di), f2b(a2 * di), f2b(a3 * di)};
    *(ushort4*)(h1b + (size_t)node * HD + g) = r;
}

// scatter one h1b row (16 bf16 feats) into int fixed-point accumulators
__device__ __forceinline__ void scat16(int* a, uint4 u0, uint4 u1) {
    atomicAdd(a + 0,  __float2int_rn(lo2f(u0.x) * FXS));
    atomicAdd(a + 1,  __float2int_rn(hi2f(u0.x) * FXS));
    atomicAdd(a + 2,  __float2int_rn(lo2f(u0.y) * FXS));
    atomicAdd(a + 3,  __float2int_rn(hi2f(u0.y) * FXS));
    atomicAdd(a + 4,  __float2int_rn(lo2f(u0.z) * FXS));
    atomicAdd(a + 5,  __float2int_rn(hi2f(u0.z) * FXS));
    atomicAdd(a + 6,  __float2int_rn(lo2f(u0.w) * FXS));
    atomicAdd(a + 7,  __float2int_rn(hi2f(u0.w) * FXS));
    atomicAdd(a + 8,  __float2int_rn(lo2f(u1.x) * FXS));
    atomicAdd(a + 9,  __float2int_rn(hi2f(u1.x) * FXS));
    atomicAdd(a + 10, __float2int_rn(lo2f(u1.y) * FXS));
    atomicAdd(a + 11, __float2int_rn(hi2f(u1.y) * FXS));
    atomicAdd(a + 12, __float2int_rn(lo2f(u1.z) * FXS));
    atomicAdd(a + 13, __float2int_rn(hi2f(u1.z) * FXS));
    atomicAdd(a + 14, __float2int_rn(lo2f(u1.w) * FXS));
    atomicAdd(a + 15, __float2int_rn(hi2f(u1.w) * FXS));
}

// ---- layer-1: per-bucket LDS scatter-accumulate (int fixed-point, native
// ds_add_u32) + ReLU + fused (h2 @ W2)*dinv.  atomicAdd(float) on LDS is a
// CAS loop on gfx950 (341 us lesson) -- int atomics are single-instruction.
__global__ __launch_bounds__(512) void k_aggs1(const int* __restrict__ boff,
                                               const unsigned int* __restrict__ csrb,
                                               const ushort* __restrict__ h1b,
                                               const float* __restrict__ dinv,
                                               const float* __restrict__ b1,
                                               const float* __restrict__ W2,
                                               float* __restrict__ g_s) {
    __shared__ int acc[BSPAN][HD + 1];   // 17.4 KB, stride-17 spreads banks
    __shared__ float w2s[HD * 2];
    __shared__ float b1s[HD];
    int b = blockIdx.x, t = threadIdx.x;
    for (int i = t; i < BSPAN * (HD + 1); i += 512) ((int*)acc)[i] = 0;
    if (t < HD * 2) w2s[t] = W2[t];
    else if (t < HD * 3) b1s[t - HD * 2] = b1[t - HD * 2];
    __syncthreads();
    int e0 = boff[b], e1 = boff[b + 1];
    int e = e0 + t;
    // 2 edges in flight: independent csrb->h1b gather chains
    for (; e + 512 < e1; e += 1024) {
        unsigned pa = csrb[e];
        unsigned pb = csrb[e + 512];
        const uint4* ra = (const uint4*)(h1b + (size_t)(pa & 0x1FFFF) * HD);
        const uint4* rb = (const uint4*)(h1b + (size_t)(pb & 0x1FFFF) * HD);
        uint4 a0 = ra[0], a1 = ra[1];
        uint4 c0 = rb[0], c1 = rb[1];
        scat16(acc[pa >> 17], a0, a1);
        scat16(acc[pb >> 17], c0, c1);
    }
    if (e < e1) {
        unsigned p = csrb[e];
        const uint4* r = (const uint4*)(h1b + (size_t)(p & 0x1FFFF) * HD);
        uint4 u0 = r[0], u1 = r[1];
        scat16(acc[p >> 17], u0, u1);
    }
    __syncthreads();
    // epilogue: 2 threads per node (8 features each), pair-reduce via shfl
    int loc = t >> 1, half = t & 1;
    int node = b * BSPAN + loc;
    if (node < NN) {
        float di = dinv[node];
        const uint4 sv = *(const uint4*)(h1b + (size_t)node * HD + half * 8);
        float sf[8] = {lo2f(sv.x), hi2f(sv.x), lo2f(sv.y), hi2f(sv.y),
                       lo2f(sv.z), hi2f(sv.z), lo2f(sv.w), hi2f(sv.w)};
        const int* a = acc[loc] + half * 8;
        const float* bb = b1s + half * 8;
        const float* ww = w2s + half * 16;
        float p0 = 0.f, p1 = 0.f;
        #pragma unroll
        for (int k = 0; k < 8; ++k) {
            float v = fmaxf(di * ((float)a[k] * FXI + sf[k]) + bb[k], 0.f);
            p0 += v * ww[k * 2];
            p1 += v * ww[k * 2 + 1];
        }
        p0 += __shfl_xor(p0, 1, 64);
        p1 += __shfl_xor(p1, 1, 64);
        if (half == 0) {
            float2 r = {p0 * di, p1 * di};
            *(float2*)(g_s + (size_t)node * 2) = r;
        }
    }
}

// ---- layer-2: per-bucket LDS scatter-accumulate (int) + bias + log_softmax ----
__global__ __launch_bounds__(512) void k_aggs2(const int* __restrict__ boff,
                                               const unsigned int* __restrict__ csrb,
                                               const float* __restrict__ g_s,
                                               const float* __restrict__ dinv,
                                               const float* __restrict__ b2,
                                               float* __restrict__ out) {
    __shared__ int acc[BSPAN * 3];   // stride-3 spreads banks
    int b = blockIdx.x, t = threadIdx.x;
    for (int i = t; i < BSPAN * 3; i += 512) acc[i] = 0;
    __syncthreads();
    int e0 = boff[b], e1 = boff[b + 1];
    int e = e0 + t;
    for (; e + 512 < e1; e += 1024) {
        unsigned pa = csrb[e];
        unsigned pb = csrb[e + 512];
        float2 va = *(const float2*)(g_s + (size_t)(pa & 0x1FFFF) * 2);
        float2 vb = *(const float2*)(g_s + (size_t)(pb & 0x1FFFF) * 2);
        int la = (pa >> 17) * 3, lb = (pb >> 17) * 3;
        atomicAdd(&acc[la],     __float2int_rn(va.x * FXS));
        atomicAdd(&acc[la + 1], __float2int_rn(va.y * FXS));
        atomicAdd(&acc[lb],     __float2int_rn(vb.x * FXS));
        atomicAdd(&acc[lb + 1], __float2int_rn(vb.y * FXS));
    }
    if (e < e1) {
        unsigned p = csrb[e];
        float2 v = *(const float2*)(g_s + (size_t)(p & 0x1FFFF) * 2);
        int l = (p >> 17) * 3;
        atomicAdd(&acc[l],     __float2int_rn(v.x * FXS));
        atomicAdd(&acc[l + 1], __float2int_rn(v.y * FXS));
    }
    __syncthreads();
    if (t < BSPAN) {
        int node = b * BSPAN + t;
        if (node < NN) {
            float di = dinv[node];
            float2 sv = *(const float2*)(g_s + (size_t)node * 2);
            float o0 = di * ((float)acc[t * 3] * FXI + sv.x) + b2[0];
            float o1 = di * ((float)acc[t * 3 + 1] * FXI + sv.y) + b2[1];
            float mx = fmaxf(o0, o1);
            float l = mx + logf(__expf(o0 - mx) + __expf(o1 - mx));
            float2 r = {o0 - l, o1 - l};
            *(float2*)(out + (size_t)node * 2) = r;
        }
    }
}

extern "C" void kernel_launch(void* const* d_in, const int* in_sizes, int n_in,
                              void* d_out, int out_size, void* d_ws, size_t ws_size,
                              hipStream_t stream) {
    const float* x   = (const float*)d_in[0];
    const int* ei    = (const int*)d_in[1];
    const int* src   = ei;
    const int* dst   = ei + NE;
    const float* W1  = (const float*)d_in[2];
    const float* b1  = (const float*)d_in[3];
    const float* W2  = (const float*)d_in[4];
    const float* b2  = (const float*)d_in[5];
    float* out = (float*)d_out;

    char* w = (char*)d_ws;
    float* dinv        = (float*)w;          w += NN * 4;
    int*   btot        = (int*)w;            w += NBKT * 4;
    int*   boff        = (int*)w;            w += (NBKT + 1) * 4;
    int*   cntmat      = (int*)w;            w += (size_t)NPB * NBKT * 4;   // 611 KB
    int*   relm        = (int*)w;            w += (size_t)NBKT * NPB * 4;   // 611 KB
    unsigned int* csrb = (unsigned int*)w;   w += (size_t)NE * 4;           // 12.8 MB
    ushort* h1b        = (ushort*)w;         w += (size_t)NN * HD * 2;      // 3.2 MB
    float* g_s         = (float*)w;          w += NN * CD * 4;

    k_cnt    <<<NPB, 512, 0, stream>>>(dst, cntmat);
    k_colscan<<<NBKT, 256, 0, stream>>>(cntmat, relm, btot);
    k_scanb  <<<1, 512, 0, stream>>>(btot, boff);
    k_part   <<<NPB, 512, 0, stream>>>(src, dst, boff, relm, csrb);
    k_deg    <<<NBKT, 512, 0, stream>>>(boff, csrb, dinv);
    k_gemm1  <<<(NN * 4 + 255) / 256, 256, 0, stream>>>(x, W1, dinv, h1b);
    k_aggs1  <<<NBKT, 512, 0, stream>>>(boff, csrb, h1b, dinv, b1, W2, g_s);
    k_aggs2  <<<NBKT, 512, 0, stream>>>(boff, csrb, g_s, dinv, b2, out);
}